// Round 6
// baseline (175.906 us; speedup 1.0000x reference)
//
#include <hip/hip_runtime.h>
#include <math.h>

// N=4096 nodes, D=256, S=32, K=4 heads, ETA=0.5.
// adj_mask is binary {0,1} (~2% density + self-loops): masked softmax ==
// exact sparse softmax over each row's neighbor set (exp(-1e9-max)==0 in fp32).
constexpr int NN = 4096;
constexpr int DD = 256;
constexpr int SS = 32;
constexpr int KK = 4;
constexpr int MAXN = 192;    // row degree: mean 83, sd 9 -> 192 = +12 sd
constexpr int SEGMAX = 96;   // per-quarter-row degree: mean ~21, sd 4.5
constexpr float ETA = 0.5f;
constexpr int RPB = 2;       // rows per block in attn_epi (grid = NN/RPB = 2048)

#define MEMFENCE() __asm__ volatile("" ::: "memory")

// __builtin_nontemporal_* needs scalar or NATIVE clang vector pointers.
typedef float nfloat4 __attribute__((ext_vector_type(4)));
__device__ __forceinline__ float4 ntload4(const float4* p) {
  nfloat4 v = __builtin_nontemporal_load((const nfloat4*)p);
  float4 r; r.x = v.x; r.y = v.y; r.z = v.z; r.w = v.w;
  return r;
}

// ---------------------------------------------------------------------------
// Kernel 1 (prep) -- identical to the round-3/5 PASSING version.
// ---------------------------------------------------------------------------
__global__ __launch_bounds__(256) void prep_kernel(
    const float* __restrict__ H, const float* __restrict__ U,
    const float* __restrict__ lp, float* __restrict__ Z,
    float* __restrict__ elp, float* __restrict__ lossp) {
  __shared__ float Hl[16][DD];   // 16 KB (Z path only)
  __shared__ float red[4];
  const int tid = threadIdx.x;

  if (blockIdx.x < 1024) {
    const int k = blockIdx.x & 3;
    const int n0 = (blockIdx.x >> 2) * 16;

    const float4* H4 = (const float4*)(H + (size_t)n0 * DD);
    float4* Hl4 = (float4*)&Hl[0][0];
    for (int i = tid; i < 16 * DD / 4; i += 256) Hl4[i] = H4[i];
    __syncthreads();

    const int s = tid & 31;
    const int n_l = (tid >> 5) & 7;   // 0..7; thread owns nodes n_l and n_l+8
    const float* Uk = U + (size_t)k * DD * SS;
    float acc0 = 0.f, acc1 = 0.f;
#pragma unroll 4
    for (int dq = 0; dq < DD / 4; dq++) {
      const float4 h0 = Hl4[n_l * (DD / 4) + dq];        // LDS broadcast b128
      const float4 h1 = Hl4[(n_l + 8) * (DD / 4) + dq];
      const float u0 = Uk[(4 * dq + 0) * SS + s];        // coalesced 128B
      const float u1 = Uk[(4 * dq + 1) * SS + s];
      const float u2 = Uk[(4 * dq + 2) * SS + s];
      const float u3 = Uk[(4 * dq + 3) * SS + s];
      acc0 += h0.x * u0 + h0.y * u1 + h0.z * u2 + h0.w * u3;
      acc1 += h1.x * u0 + h1.y * u1 + h1.z * u2 + h1.w * u3;
    }
    Z[((size_t)k * NN + n0 + n_l) * SS + s] = acc0;
    Z[((size_t)k * NN + n0 + n_l + 8) * SS + s] = acc1;
  } else {
    // ---- orth path: one (k<=l) pair per block ----
    const int pair = blockIdx.x - 1024;
    if (pair == 0 && tid < KK * SS) elp[tid] = expf(lp[tid]);
    const int pk[10] = {0, 0, 0, 0, 1, 1, 1, 2, 2, 3};
    const int pl[10] = {0, 1, 2, 3, 1, 2, 3, 2, 3, 3};
    const int k = pk[pair], l = pl[pair];
    const int b = tid & 31;
    const int a0 = tid >> 5;             // cells a = 4*a0 .. 4*a0+3 (contiguous)
    float4 acc = {0.f, 0.f, 0.f, 0.f};
    const float4* Uk4 = (const float4*)(U + (size_t)k * DD * SS);
    const float* Ul = U + (size_t)l * DD * SS;
    for (int d = 0; d < DD; d++) {
      const float ub = Ul[(size_t)d * SS + b];             // coalesced 128B
      const float4 ua = Uk4[d * (SS / 4) + a0];            // 2 VMEM/d total
      acc.x += ua.x * ub; acc.y += ua.y * ub;
      acc.z += ua.z * ub; acc.w += ua.w * ub;
    }
    const int abase = 4 * a0;
    float cvx = acc.x - ((k == l && abase + 0 == b) ? 1.0f : 0.0f);
    float cvy = acc.y - ((k == l && abase + 1 == b) ? 1.0f : 0.0f);
    float cvz = acc.z - ((k == l && abase + 2 == b) ? 1.0f : 0.0f);
    float cvw = acc.w - ((k == l && abase + 3 == b) ? 1.0f : 0.0f);
    float tot = cvx * cvx + cvy * cvy + cvz * cvz + cvw * cvw;
#pragma unroll
    for (int off = 32; off >= 1; off >>= 1) tot += __shfl_xor(tot, off);
    if ((tid & 63) == 0) red[tid >> 6] = tot;
    __syncthreads();
    if (tid == 0) lossp[pair] = red[0] + red[1] + red[2] + red[3];
  }
}

// ---------------------------------------------------------------------------
// Kernel 2 (attn + fused epilogue): RPB=2 rows per block, 2048 blocks.
//   Occupancy: 8 blocks/CU (2048 thr/CU, the max) -- round-5 counters showed
//   the old 1024-block grid capped occupancy at 35% and HBM at 0.92 TB/s.
//   Structure (3 barriers total, was ~9):
//     1) hoist BOTH rows' mask loads (8 independent nt float4/thread, 8-deep
//        MLP), then ballot-compact row 0 and row 1 into segn[r][wv][]
//     2) barrier; merge both rows into packed nbr[r][]
//     3) barrier; wave k = head k: single-pass online softmax (verified
//        round-3 math, unchanged) for row 0 then row 1 -> AOl[r] in LDS
//     4) barrier; fused epilogue for the 2 rows.
// ---------------------------------------------------------------------------
__global__ __launch_bounds__(256, 8) void attn_epi(
    const float* __restrict__ mask, const float* __restrict__ Z,
    const float* __restrict__ elp, const float* __restrict__ lossp,
    const float* __restrict__ H, const float* __restrict__ U,
    const float* __restrict__ thr, float* __restrict__ Hout,
    float* __restrict__ loss) {
  const int tid = threadIdx.x;
  const int wv = tid >> 6;
  const int lane = tid & 63;
  const int bid = blockIdx.x;

  __shared__ int segn[RPB][4][SEGMAX];   // 3 KB
  __shared__ int segc[RPB][4];
  __shared__ int nbr[RPB][MAXN];         // 1.5 KB
  __shared__ float AOl[RPB][KK * SS];    // 1 KB

  if (bid == 0 && tid == 0) {
    float t = 0.f;
#pragma unroll
    for (int i = 0; i < 10; i++) t += lossp[i];
    loss[0] = t;
  }

  const unsigned long long lt = (1ULL << lane) - 1ULL;

  // --- scan: hoist all mask loads for both rows (8-deep MLP), then ballots --
  {
    const float4* m4 = (const float4*)(mask + (size_t)(bid * RPB) * NN);
    const int base = wv * 256 + lane;            // float4 index within a row
    float4 v[RPB][4];
#pragma unroll
    for (int r = 0; r < RPB; r++)
#pragma unroll
      for (int it = 0; it < 4; it++)
        v[r][it] = ntload4(&m4[(size_t)r * (NN / 4) + base + it * 64]);

#pragma unroll
    for (int r = 0; r < RPB; r++) {
      int cnt = 0;
#pragma unroll
      for (int it = 0; it < 4; it++) {
        const int i = base + it * 64;            // coalesced within wave
        const float4 vv = v[r][it];
        unsigned long long bb;
        bb = __ballot(vv.x > 0.5f);
        if (vv.x > 0.5f) { const int p = cnt + (int)__popcll(bb & lt); if (p < SEGMAX) segn[r][wv][p] = 4 * i; }
        cnt += (int)__popcll(bb);
        bb = __ballot(vv.y > 0.5f);
        if (vv.y > 0.5f) { const int p = cnt + (int)__popcll(bb & lt); if (p < SEGMAX) segn[r][wv][p] = 4 * i + 1; }
        cnt += (int)__popcll(bb);
        bb = __ballot(vv.z > 0.5f);
        if (vv.z > 0.5f) { const int p = cnt + (int)__popcll(bb & lt); if (p < SEGMAX) segn[r][wv][p] = 4 * i + 2; }
        cnt += (int)__popcll(bb);
        bb = __ballot(vv.w > 0.5f);
        if (vv.w > 0.5f) { const int p = cnt + (int)__popcll(bb & lt); if (p < SEGMAX) segn[r][wv][p] = 4 * i + 3; }
        cnt += (int)__popcll(bb);
      }
      if (lane == 0) segc[r][wv] = min(cnt, SEGMAX);
    }
  }
  MEMFENCE();
  __syncthreads();

  // --- merge segments into packed nbr[r][] (both rows) ---
  int ctot[RPB];
#pragma unroll
  for (int r = 0; r < RPB; r++) {
    const int c0 = segc[r][0], c1 = segc[r][1];
    const int c2 = segc[r][2], c3 = segc[r][3];
    const int offs[4] = {0, c0, c0 + c1, c0 + c1 + c2};
    ctot[r] = min(c0 + c1 + c2 + c3, MAXN);
    const int myc = segc[r][wv];
    const int myoff = offs[wv];
    for (int i = lane; i < myc; i += 64) {
      const int p = myoff + i;
      if (p < MAXN) nbr[r][p] = segn[r][wv][i];
    }
  }
  MEMFENCE();
  __syncthreads();

  // --- attention: wave k = head k; rows r = 0..RPB-1 sequentially ---
  const int p_sub = lane >> 3;   // neighbor slot within chunk (bits 3..5)
  const int sq = lane & 7;       // float4 slice of the 32-dim row (bits 0..2)
  const float inv_sqrt_s = 0.17677669529663687f;  // 1/sqrt(32)
  const int k = wv;
  const float* Zk = Z + (size_t)k * NN * SS;

#pragma unroll
  for (int r = 0; r < RPB; r++) {
    const int row = bid * RPB + r;
    const int c = ctot[r];
    const int* nb = &nbr[r][0];

    float4 q4;
    {
      const float4 a = ((const float4*)(Z + ((size_t)k * NN + row) * SS))[sq];
      const float4 e = ((const float4*)(elp + k * SS))[sq];
      q4.x = a.x * e.x; q4.y = a.y * e.y; q4.z = a.z * e.z; q4.w = a.w * e.w;
    }

    float m = -3.0e38f;
    float wsum = 0.f;
    float4 o4 = {0.f, 0.f, 0.f, 0.f};

    bool aA = p_sub < c, aB = (p_sub + 8) < c;
    float4 zA = {0.f, 0.f, 0.f, 0.f}, zB = {0.f, 0.f, 0.f, 0.f};
    if (aA) zA = ((const float4*)(Zk + (size_t)nb[p_sub] * SS))[sq];
    if (aB) zB = ((const float4*)(Zk + (size_t)nb[p_sub + 8] * SS))[sq];

    for (int p0 = 0; p0 < c; p0 += 16) {
      // issue next chunk's gathers first (overlap with this chunk's math)
      const int pa_n = p0 + 16 + p_sub;
      const int pb_n = pa_n + 8;
      const bool aA_n = pa_n < c, aB_n = pb_n < c;
      float4 zA_n = {0.f, 0.f, 0.f, 0.f}, zB_n = {0.f, 0.f, 0.f, 0.f};
      if (aA_n) zA_n = ((const float4*)(Zk + (size_t)nb[pa_n] * SS))[sq];
      if (aB_n) zB_n = ((const float4*)(Zk + (size_t)nb[pb_n] * SS))[sq];

      float dA = q4.x * zA.x + q4.y * zA.y + q4.z * zA.z + q4.w * zA.w;
      float dB = q4.x * zB.x + q4.y * zB.y + q4.z * zB.z + q4.w * zB.w;
      dA += __shfl_xor(dA, 1); dB += __shfl_xor(dB, 1);
      dA += __shfl_xor(dA, 2); dB += __shfl_xor(dB, 2);
      dA += __shfl_xor(dA, 4); dB += __shfl_xor(dB, 4);  // full dot, all sq lanes
      dA = aA ? dA * inv_sqrt_s : -3.0e38f;
      dB = aB ? dB * inv_sqrt_s : -3.0e38f;
      float cm = fmaxf(dA, dB);
      cm = fmaxf(cm, __shfl_xor(cm, 8));
      cm = fmaxf(cm, __shfl_xor(cm, 16));
      cm = fmaxf(cm, __shfl_xor(cm, 32));
      const float mn = fmaxf(m, cm);
      const float sc = __expf(m - mn);   // first iter: exp(-inf) == 0
      m = mn;
      const float wA = __expf(dA - m);   // invalid slot: exp(-3e38-m) == 0
      const float wB = __expf(dB - m);
      o4.x = o4.x * sc + wA * zA.x + wB * zB.x;
      o4.y = o4.y * sc + wA * zA.y + wB * zB.y;
      o4.z = o4.z * sc + wA * zA.z + wB * zB.z;
      o4.w = o4.w * sc + wA * zA.w + wB * zB.w;
      wsum = wsum * sc + wA + wB;

      zA = zA_n; zB = zB_n; aA = aA_n; aB = aB_n;
    }
#pragma unroll
    for (int off = 8; off <= 32; off <<= 1) {
      o4.x += __shfl_xor(o4.x, off);
      o4.y += __shfl_xor(o4.y, off);
      o4.z += __shfl_xor(o4.z, off);
      o4.w += __shfl_xor(o4.w, off);
      wsum += __shfl_xor(wsum, off);
    }
    const float invl = 1.0f / wsum;   // c >= 1 (self-loop) -> wsum > 0
    if (p_sub == 0) {
      float4 o;
      o.x = o4.x * invl; o.y = o4.y * invl;
      o.z = o4.z * invl; o.w = o4.w * invl;
      ((float4*)&AOl[r][0])[k * 8 + sq] = o;   // AO row stays in LDS
    }
  }
  MEMFENCE();
  __syncthreads();

  // --- fused epilogue: Hout = softthresh(H + ETA * AOl @ Ufl) ---
  {
    const int r0 = bid * RPB;
    const int d = tid;
    float acc[RPB];
#pragma unroll
    for (int r = 0; r < RPB; r++) acc[r] = 0.f;
    const float4* U4 = (const float4*)U;
    const float4* AOl4 = (const float4*)&AOl[0][0];
#pragma unroll
    for (int kk = 0; kk < KK; kk++) {
      const int ubase = (kk * DD + d) * (SS / 4);
#pragma unroll
      for (int sq2 = 0; sq2 < SS / 4; sq2++) {
        const float4 u = U4[ubase + sq2];   // thread's 128B row of U[kk][d][:]
#pragma unroll
        for (int r = 0; r < RPB; r++) {
          const float4 a = AOl4[r * (KK * SS / 4) + kk * (SS / 4) + sq2];
          acc[r] += u.x * a.x + u.y * a.y + u.z * a.z + u.w * a.w;
        }
      }
    }
    const float tv = thr[d];
#pragma unroll
    for (int r = 0; r < RPB; r++) {
      const float h =
          __builtin_nontemporal_load(&H[(size_t)(r0 + r) * DD + d]) + ETA * acc[r];
      const float ab = fabsf(h) - tv;
      const float o = (ab > 0.0f) ? copysignf(ab, h) : 0.0f;
      __builtin_nontemporal_store(o, &Hout[(size_t)(r0 + r) * DD + d]);
    }
  }
}

// ---------------------------------------------------------------------------
extern "C" void kernel_launch(void* const* d_in, const int* in_sizes, int n_in,
                              void* d_out, int out_size, void* d_ws, size_t ws_size,
                              hipStream_t stream) {
  const float* H    = (const float*)d_in[0];
  const float* mask = (const float*)d_in[1];
  const float* U    = (const float*)d_in[2];
  const float* lp   = (const float*)d_in[3];
  const float* thr  = (const float*)d_in[4];

  float* Hout = (float*)d_out;
  float* loss = Hout + (size_t)NN * DD;      // outputs: [N*D] + [1]

  float* Z     = (float*)d_ws;               // [K][N][S]   2 MB (16B aligned)
  float* elp   = Z + (size_t)KK * NN * SS;   // [K*S]
  float* lossp = elp + KK * SS;              // [10]

  prep_kernel<<<1034, 256, 0, stream>>>(H, U, lp, Z, elp, lossp);
  attn_epi<<<NN / RPB, 256, 0, stream>>>(mask, Z, elp, lossp, H, U, thr, Hout, loss);
}

// Round 10
// 149.967 us; speedup vs baseline: 1.1730x; 1.1730x over previous
//
#include <hip/hip_runtime.h>
#include <math.h>

// N=4096 nodes, D=256, S=32, K=4 heads, ETA=0.5.
// adj_mask is binary {0,1} (~2% density + self-loops): masked softmax ==
// exact sparse softmax over each row's neighbor set (exp(-1e9-max)==0 in fp32).
constexpr int NN = 4096;
constexpr int DD = 256;
constexpr int SS = 32;
constexpr int KK = 4;
constexpr int MAXN = 192;    // row degree: mean 83, sd 9 -> 192 = +12 sd
constexpr float ETA = 0.5f;
constexpr int RPB = 2;       // rows per block in attn_epi (grid = NN/RPB = 2048)

// prep grid layout: [0,1024) Z-GEMM | [1024,1034) orth | [1034,2058) scan |
//                   [2058,2074) U-transpose
constexpr int SCAN0 = 1034;
constexpr int TRAN0 = 2058;
constexpr int PREP_GRID = 2074;

#define MEMFENCE() __asm__ volatile("" ::: "memory")

// __builtin_nontemporal_* needs scalar or NATIVE clang vector pointers.
typedef float nfloat4 __attribute__((ext_vector_type(4)));
__device__ __forceinline__ float4 ntload4(const float4* p) {
  nfloat4 v = __builtin_nontemporal_load((const nfloat4*)p);
  float4 r; r.x = v.x; r.y = v.y; r.z = v.z; r.w = v.w;
  return r;
}
__device__ __forceinline__ void ntstore4(float4* p, float4 v) {
  nfloat4 t; t.x = v.x; t.y = v.y; t.z = v.z; t.w = v.w;
  __builtin_nontemporal_store(t, (nfloat4*)p);
}

// ---------------------------------------------------------------------------
// Kernel 1 (prep): Z-GEMM + orth-loss (verified, unchanged) + mask scan
// (one WAVE per row, 8-deep nt loads, no barriers -> packed nbrg/cntg) +
// U transpose -> Ut[(k*32+s)][d] for the coalesced epilogue.
// Scan is pure-BW and overlaps the compute-heavy Z-GEMM blocks.
// ---------------------------------------------------------------------------
__global__ __launch_bounds__(256) void prep_kernel(
    const float* __restrict__ H, const float* __restrict__ U,
    const float* __restrict__ lp, const float* __restrict__ mask,
    float* __restrict__ Z, float* __restrict__ Ut, float* __restrict__ elp,
    float* __restrict__ lossp, int* __restrict__ cntg, int* __restrict__ nbrg) {
  __shared__ float Hl[16][DD];   // 16 KB (Z path only)
  __shared__ float red[4];
  const int tid = threadIdx.x;
  const int bid = blockIdx.x;

  if (bid < 1024) {
    const int k = bid & 3;
    const int n0 = (bid >> 2) * 16;

    const float4* H4 = (const float4*)(H + (size_t)n0 * DD);
    float4* Hl4 = (float4*)&Hl[0][0];
    for (int i = tid; i < 16 * DD / 4; i += 256) Hl4[i] = H4[i];
    __syncthreads();

    const int s = tid & 31;
    const int n_l = (tid >> 5) & 7;   // 0..7; thread owns nodes n_l and n_l+8
    const float* Uk = U + (size_t)k * DD * SS;
    float acc0 = 0.f, acc1 = 0.f;
#pragma unroll 4
    for (int dq = 0; dq < DD / 4; dq++) {
      const float4 h0 = Hl4[n_l * (DD / 4) + dq];        // LDS broadcast b128
      const float4 h1 = Hl4[(n_l + 8) * (DD / 4) + dq];
      const float u0 = Uk[(4 * dq + 0) * SS + s];        // coalesced 128B
      const float u1 = Uk[(4 * dq + 1) * SS + s];
      const float u2 = Uk[(4 * dq + 2) * SS + s];
      const float u3 = Uk[(4 * dq + 3) * SS + s];
      acc0 += h0.x * u0 + h0.y * u1 + h0.z * u2 + h0.w * u3;
      acc1 += h1.x * u0 + h1.y * u1 + h1.z * u2 + h1.w * u3;
    }
    Z[((size_t)k * NN + n0 + n_l) * SS + s] = acc0;
    Z[((size_t)k * NN + n0 + n_l + 8) * SS + s] = acc1;
  } else if (bid < SCAN0) {
    // ---- orth path: one (k<=l) pair per block ----
    const int pair = bid - 1024;
    if (pair == 0 && tid < KK * SS) elp[tid] = expf(lp[tid]);
    const int pk[10] = {0, 0, 0, 0, 1, 1, 1, 2, 2, 3};
    const int pl[10] = {0, 1, 2, 3, 1, 2, 3, 2, 3, 3};
    const int k = pk[pair], l = pl[pair];
    const int b = tid & 31;
    const int a0 = tid >> 5;             // cells a = 4*a0 .. 4*a0+3 (contiguous)
    float4 acc = {0.f, 0.f, 0.f, 0.f};
    const float4* Uk4 = (const float4*)(U + (size_t)k * DD * SS);
    const float* Ul = U + (size_t)l * DD * SS;
    for (int d = 0; d < DD; d++) {
      const float ub = Ul[(size_t)d * SS + b];             // coalesced 128B
      const float4 ua = Uk4[d * (SS / 4) + a0];            // 2 VMEM/d total
      acc.x += ua.x * ub; acc.y += ua.y * ub;
      acc.z += ua.z * ub; acc.w += ua.w * ub;
    }
    const int abase = 4 * a0;
    float cvx = acc.x - ((k == l && abase + 0 == b) ? 1.0f : 0.0f);
    float cvy = acc.y - ((k == l && abase + 1 == b) ? 1.0f : 0.0f);
    float cvz = acc.z - ((k == l && abase + 2 == b) ? 1.0f : 0.0f);
    float cvw = acc.w - ((k == l && abase + 3 == b) ? 1.0f : 0.0f);
    float tot = cvx * cvx + cvy * cvy + cvz * cvz + cvw * cvw;
#pragma unroll
    for (int off = 32; off >= 1; off >>= 1) tot += __shfl_xor(tot, off);
    if ((tid & 63) == 0) red[tid >> 6] = tot;
    __syncthreads();
    if (tid == 0) lossp[pair] = red[0] + red[1] + red[2] + red[3];
  } else if (bid < TRAN0) {
    // ---- mask scan: ONE WAVE PER ROW, no barriers, no LDS ----
    const int wv = tid >> 6;
    const int lane = tid & 63;
    const int row = (bid - SCAN0) * 4 + wv;
    const float4* m4 = (const float4*)(mask + (size_t)row * NN);
    int* ng = nbrg + (size_t)row * MAXN;
    const unsigned long long lt = (1ULL << lane) - 1ULL;
    int cnt = 0;
#pragma unroll
    for (int bt = 0; bt < 2; bt++) {           // two 8-deep load batches
      float4 v[8];
#pragma unroll
      for (int j = 0; j < 8; j++)
        v[j] = ntload4(&m4[(bt * 8 + j) * 64 + lane]);
#pragma unroll
      for (int j = 0; j < 8; j++) {
        const int i = (bt * 8 + j) * 64 + lane;   // float4 index in row
        const float4 vv = v[j];
        unsigned long long bb;
        bb = __ballot(vv.x > 0.5f);
        if (vv.x > 0.5f) { const int p = cnt + (int)__popcll(bb & lt); if (p < MAXN) ng[p] = 4 * i; }
        cnt += (int)__popcll(bb);
        bb = __ballot(vv.y > 0.5f);
        if (vv.y > 0.5f) { const int p = cnt + (int)__popcll(bb & lt); if (p < MAXN) ng[p] = 4 * i + 1; }
        cnt += (int)__popcll(bb);
        bb = __ballot(vv.z > 0.5f);
        if (vv.z > 0.5f) { const int p = cnt + (int)__popcll(bb & lt); if (p < MAXN) ng[p] = 4 * i + 2; }
        cnt += (int)__popcll(bb);
        bb = __ballot(vv.w > 0.5f);
        if (vv.w > 0.5f) { const int p = cnt + (int)__popcll(bb & lt); if (p < MAXN) ng[p] = 4 * i + 3; }
        cnt += (int)__popcll(bb);
      }
    }
    if (lane == 0) cntg[row] = min(cnt, MAXN);
  } else {
    // ---- U transpose: Ut[(k*32+s)][d] = U[k][d][s]; 16 blocks x 8 pairs ----
    const int pair = (bid - TRAN0) * 8 + (tid >> 5);   // (k,s) in [0,128)
    const int k = pair >> 5, s = pair & 31;
    const int l = tid & 31;
#pragma unroll
    for (int j = 0; j < 8; j++) {
      const int d = l * 8 + j;
      Ut[(size_t)pair * DD + d] = U[((size_t)k * DD + d) * SS + s];
    }
  }
}

// ---------------------------------------------------------------------------
// Kernel 2 (attn + fused epilogue): RPB=2 rows/block, 2048 blocks, 4 waves.
//   NO mask scan here anymore: nbr lists come precompacted from prep.
//   NO launch_bounds min-waves pin (round-6 lesson: VGPR=32 killed MLP).
//   Flow: load cnt/nbr (coalesced) -> barrier -> per-wave head k, rows 0..1
//   single-pass online softmax w/ 2-deep pipelined gathers -> AOl in LDS ->
//   barrier -> COALESCED epilogue via Ut (lane-contiguous float4, LDS-reduced
//   partials) -> barrier -> softthresh + nt store.
// ---------------------------------------------------------------------------
__global__ __launch_bounds__(256) void attn_epi(
    const int* __restrict__ nbrg, const int* __restrict__ cntg,
    const float* __restrict__ Z, const float* __restrict__ elp,
    const float* __restrict__ lossp, const float* __restrict__ H,
    const float* __restrict__ Ut, const float* __restrict__ thr,
    float* __restrict__ Hout, float* __restrict__ loss) {
  const int tid = threadIdx.x;
  const int wv = tid >> 6;
  const int lane = tid & 63;
  const int bid = blockIdx.x;

  __shared__ int nbr[RPB][MAXN];         // 1.5 KB
  __shared__ float AOl[RPB][KK * SS];    // 1 KB
  __shared__ float part[RPB][KK][64][4]; // 8 KB epilogue partials

  if (bid == 0 && tid == 0) {
    float t = 0.f;
#pragma unroll
    for (int i = 0; i < 10; i++) t += lossp[i];
    loss[0] = t;
  }

  const int row0 = bid * RPB;
  const int c0 = cntg[row0];
  const int c1 = cntg[row0 + 1];
  if (tid < c0) nbr[0][tid] = nbrg[(size_t)row0 * MAXN + tid];
  if (tid < c1) nbr[1][tid] = nbrg[(size_t)(row0 + 1) * MAXN + tid];
  MEMFENCE();
  __syncthreads();

  // --- attention: wave k = head k; rows r = 0..RPB-1 sequentially ---
  const int p_sub = lane >> 3;   // neighbor slot within chunk (bits 3..5)
  const int sq = lane & 7;       // float4 slice of the 32-dim row (bits 0..2)
  const float inv_sqrt_s = 0.17677669529663687f;  // 1/sqrt(32)
  const int k = wv;
  const float* Zk = Z + (size_t)k * NN * SS;

#pragma unroll
  for (int r = 0; r < RPB; r++) {
    const int row = row0 + r;
    const int c = r ? c1 : c0;
    const int* nb = &nbr[r][0];

    float4 q4;
    {
      const float4 a = ((const float4*)(Z + ((size_t)k * NN + row) * SS))[sq];
      const float4 e = ((const float4*)(elp + k * SS))[sq];
      q4.x = a.x * e.x; q4.y = a.y * e.y; q4.z = a.z * e.z; q4.w = a.w * e.w;
    }

    float m = -3.0e38f;
    float wsum = 0.f;
    float4 o4 = {0.f, 0.f, 0.f, 0.f};

    bool aA = p_sub < c, aB = (p_sub + 8) < c;
    float4 zA = {0.f, 0.f, 0.f, 0.f}, zB = {0.f, 0.f, 0.f, 0.f};
    if (aA) zA = ((const float4*)(Zk + (size_t)nb[p_sub] * SS))[sq];
    if (aB) zB = ((const float4*)(Zk + (size_t)nb[p_sub + 8] * SS))[sq];

    for (int p0 = 0; p0 < c; p0 += 16) {
      // issue next chunk's gathers first (overlap with this chunk's math)
      const int pa_n = p0 + 16 + p_sub;
      const int pb_n = pa_n + 8;
      const bool aA_n = pa_n < c, aB_n = pb_n < c;
      float4 zA_n = {0.f, 0.f, 0.f, 0.f}, zB_n = {0.f, 0.f, 0.f, 0.f};
      if (aA_n) zA_n = ((const float4*)(Zk + (size_t)nb[pa_n] * SS))[sq];
      if (aB_n) zB_n = ((const float4*)(Zk + (size_t)nb[pb_n] * SS))[sq];

      float dA = q4.x * zA.x + q4.y * zA.y + q4.z * zA.z + q4.w * zA.w;
      float dB = q4.x * zB.x + q4.y * zB.y + q4.z * zB.z + q4.w * zB.w;
      dA += __shfl_xor(dA, 1); dB += __shfl_xor(dB, 1);
      dA += __shfl_xor(dA, 2); dB += __shfl_xor(dB, 2);
      dA += __shfl_xor(dA, 4); dB += __shfl_xor(dB, 4);  // full dot, all sq lanes
      dA = aA ? dA * inv_sqrt_s : -3.0e38f;
      dB = aB ? dB * inv_sqrt_s : -3.0e38f;
      float cm = fmaxf(dA, dB);
      cm = fmaxf(cm, __shfl_xor(cm, 8));
      cm = fmaxf(cm, __shfl_xor(cm, 16));
      cm = fmaxf(cm, __shfl_xor(cm, 32));
      const float mn = fmaxf(m, cm);
      const float sc = __expf(m - mn);   // first iter: exp(-inf) == 0
      m = mn;
      const float wA = __expf(dA - m);   // invalid slot: exp(-3e38-m) == 0
      const float wB = __expf(dB - m);
      o4.x = o4.x * sc + wA * zA.x + wB * zB.x;
      o4.y = o4.y * sc + wA * zA.y + wB * zB.y;
      o4.z = o4.z * sc + wA * zA.z + wB * zB.z;
      o4.w = o4.w * sc + wA * zA.w + wB * zB.w;
      wsum = wsum * sc + wA + wB;

      zA = zA_n; zB = zB_n; aA = aA_n; aB = aB_n;
    }
#pragma unroll
    for (int off = 8; off <= 32; off <<= 1) {
      o4.x += __shfl_xor(o4.x, off);
      o4.y += __shfl_xor(o4.y, off);
      o4.z += __shfl_xor(o4.z, off);
      o4.w += __shfl_xor(o4.w, off);
      wsum += __shfl_xor(wsum, off);
    }
    const float invl = 1.0f / wsum;   // c >= 1 (self-loop) -> wsum > 0
    if (p_sub == 0) {
      float4 o;
      o.x = o4.x * invl; o.y = o4.y * invl;
      o.z = o4.z * invl; o.w = o4.w * invl;
      ((float4*)&AOl[r][0])[k * 8 + sq] = o;   // AO row stays in LDS
    }
  }
  MEMFENCE();
  __syncthreads();

  // --- coalesced epilogue: wave k accumulates its head's contribution ---
  // lane owns d-quad `lane`; Ut rows are contiguous 1KB -> full line use.
  {
    const float4* Ut4 = (const float4*)Ut;
    float4 acc0 = {0.f, 0.f, 0.f, 0.f};
    float4 acc1 = {0.f, 0.f, 0.f, 0.f};
#pragma unroll 8
    for (int s = 0; s < SS; s++) {
      const int ks = k * SS + s;
      const float4 u = Ut4[(size_t)ks * (DD / 4) + lane];  // coalesced 1KB/wave
      const float a0 = AOl[0][ks];                         // LDS broadcast
      const float a1 = AOl[1][ks];
      acc0.x += a0 * u.x; acc0.y += a0 * u.y; acc0.z += a0 * u.z; acc0.w += a0 * u.w;
      acc1.x += a1 * u.x; acc1.y += a1 * u.y; acc1.z += a1 * u.z; acc1.w += a1 * u.w;
    }
    ((float4*)&part[0][k][lane][0])[0] = acc0;
    ((float4*)&part[1][k][lane][0])[0] = acc1;
  }
  MEMFENCE();
  __syncthreads();

  if (tid < 64 * RPB) {
    const int r = tid >> 6;
    const int l2 = tid & 63;
    const float4 p0 = ((const float4*)&part[r][0][l2][0])[0];
    const float4 p1 = ((const float4*)&part[r][1][l2][0])[0];
    const float4 p2 = ((const float4*)&part[r][2][l2][0])[0];
    const float4 p3 = ((const float4*)&part[r][3][l2][0])[0];
    const float4 h4 = ntload4(&((const float4*)(H + (size_t)(row0 + r) * DD))[l2]);
    const float4 t4 = ((const float4*)thr)[l2];
    float4 o;
    const float hx = h4.x + ETA * (p0.x + p1.x + p2.x + p3.x);
    const float hy = h4.y + ETA * (p0.y + p1.y + p2.y + p3.y);
    const float hz = h4.z + ETA * (p0.z + p1.z + p2.z + p3.z);
    const float hw = h4.w + ETA * (p0.w + p1.w + p2.w + p3.w);
    const float ax = fabsf(hx) - t4.x, ay = fabsf(hy) - t4.y;
    const float az = fabsf(hz) - t4.z, aw = fabsf(hw) - t4.w;
    o.x = (ax > 0.f) ? copysignf(ax, hx) : 0.f;
    o.y = (ay > 0.f) ? copysignf(ay, hy) : 0.f;
    o.z = (az > 0.f) ? copysignf(az, hz) : 0.f;
    o.w = (aw > 0.f) ? copysignf(aw, hw) : 0.f;
    ntstore4(&((float4*)(Hout + (size_t)(row0 + r) * DD))[l2], o);
  }
}

// ---------------------------------------------------------------------------
extern "C" void kernel_launch(void* const* d_in, const int* in_sizes, int n_in,
                              void* d_out, int out_size, void* d_ws, size_t ws_size,
                              hipStream_t stream) {
  const float* H    = (const float*)d_in[0];
  const float* mask = (const float*)d_in[1];
  const float* U    = (const float*)d_in[2];
  const float* lp   = (const float*)d_in[3];
  const float* thr  = (const float*)d_in[4];

  float* Hout = (float*)d_out;
  float* loss = Hout + (size_t)NN * DD;      // outputs: [N*D] + [1]

  float* Z     = (float*)d_ws;               // [K][N][S]       2 MB
  float* Ut    = Z + (size_t)KK * NN * SS;   // [(K*S)][D]      128 KB
  float* elp   = Ut + (size_t)KK * SS * DD;  // [K*S]
  float* lossp = elp + KK * SS;              // [16] (10 used)
  int*   cntg  = (int*)(lossp + 16);         // [N]
  int*   nbrg  = cntg + NN;                  // [N][MAXN]       3 MB

  prep_kernel<<<PREP_GRID, 256, 0, stream>>>(H, U, lp, mask, Z, Ut, elp,
                                             lossp, cntg, nbrg);
  attn_epi<<<NN / RPB, 256, 0, stream>>>(nbrg, cntg, Z, elp, lossp, H, Ut,
                                         thr, Hout, loss);
}